// Round 11
// baseline (17701.889 us; speedup 1.0000x reference)
//
#include <hip/hip_runtime.h>
#include <hip/hip_fp8.h>

typedef unsigned short u16;
typedef unsigned char u8;
typedef unsigned int u32;
typedef long long i64;
typedef __attribute__((ext_vector_type(2))) i64 i64x2;
typedef __attribute__((ext_vector_type(8))) short short8;
typedef __attribute__((ext_vector_type(4))) float f32x4;

constexpr int HD = 2048;     // hidden / K (bytes in fp8)
constexpr int NR = 4096;     // rows B*S
constexpr int VO = 128000;   // vocab

// ---------------- fp8 path geometry: 256^2 tile, K-tile = 64 B ----------------
constexpr int NMB8 = NR / 256;    // 16
constexpr int NVB8 = VO / 256;    // 500
constexpr int NT8  = HD / 64;     // 32 K-tiles
constexpr float XSCALE = 32.0f;
constexpr float WSCALE = 16384.0f;
constexpr float UNSCALE = 1.0f / (XSCALE * WSCALE);

// ws layout (fp8 path)
constexpr size_t OFF_X8  = 0;                          // 8,388,608
constexpr size_t OFF_W8  = 8388608;                    // 262,144,000
constexpr size_t OFF_PMX = OFF_W8 + 262144000;         // 8,192,000
constexpr size_t OFF_PSM = OFF_PMX + 8192000;
constexpr size_t OFF_LSE = OFF_PSM + 8192000;
constexpr size_t OFF_TL  = OFF_LSE + 16384;
constexpr size_t NEED_NEW = OFF_TL + 16384;            // ~287 MB

// ws layout, fallback (round-1 bf16 128^2, proven)
constexpr int NVBF = VO / 128;
constexpr int NMBF = NR / 128;
constexpr size_t FB_XB   = 0;
constexpr size_t FB_PMAX = 16777216;
constexpr size_t FB_PSUM = FB_PMAX + 16384000;
constexpr size_t FB_LSE  = FB_PSUM + 16384000;
constexpr size_t FB_TL   = FB_LSE + (size_t)NR * 4;

// fallback swizzle
__device__ __forceinline__ u32 swz16(u32 a) { return a ^ (((a >> 7) & 3u) << 4); }

__device__ __forceinline__ u8 f2e4m3(float f) {
  return (u8)__hip_cvt_float_to_fp8(f, __HIP_SATFINITE, __HIP_E4M3);
}

// ---------------- x f32 -> fp8, kk-interleaved layout ----------------
// Per row, per 64B K-block: cell q (16B) holds elements k = kk*32 + q*8 + b
// at byte kk*8+b. One 16B LDS cell = a lane's full K=64 operand (both kk
// halves) -> single ds_read_b128 per fragment.
__global__ __launch_bounds__(256) void cvt_x8_kernel(const float* __restrict__ x,
                                                     u8* __restrict__ x8) {
  const long c = (long)blockIdx.x * 256 + threadIdx.x;   // 16B cell index
  const long row = c >> 7;                                // 128 cells/row
  const int ci = (int)(c & 127);
  const int tb = ci >> 2, q = ci & 3;
  const float* base = x + row * HD + tb * 64 + q * 8;
  float4 a0 = *reinterpret_cast<const float4*>(base);
  float4 a1 = *reinterpret_cast<const float4*>(base + 4);
  float4 a2 = *reinterpret_cast<const float4*>(base + 32);
  float4 a3 = *reinterpret_cast<const float4*>(base + 36);
  union { u8 b[16]; uint4 v; } p;
  p.b[0] = f2e4m3(a0.x * XSCALE); p.b[1] = f2e4m3(a0.y * XSCALE);
  p.b[2] = f2e4m3(a0.z * XSCALE); p.b[3] = f2e4m3(a0.w * XSCALE);
  p.b[4] = f2e4m3(a1.x * XSCALE); p.b[5] = f2e4m3(a1.y * XSCALE);
  p.b[6] = f2e4m3(a1.z * XSCALE); p.b[7] = f2e4m3(a1.w * XSCALE);
  p.b[8]  = f2e4m3(a2.x * XSCALE); p.b[9]  = f2e4m3(a2.y * XSCALE);
  p.b[10] = f2e4m3(a2.z * XSCALE); p.b[11] = f2e4m3(a2.w * XSCALE);
  p.b[12] = f2e4m3(a3.x * XSCALE); p.b[13] = f2e4m3(a3.y * XSCALE);
  p.b[14] = f2e4m3(a3.z * XSCALE); p.b[15] = f2e4m3(a3.w * XSCALE);
  reinterpret_cast<uint4*>(x8)[c] = p.v;
}

// ---------------- W f32 -> fp8, same kk-interleaved layout ----------------
__global__ __launch_bounds__(256) void cvt_w8_kernel(const float* __restrict__ W,
                                                     u8* __restrict__ w8) {
  const long total = (long)VO * HD / 16;                 // cells
  long c = (long)blockIdx.x * 256 + threadIdx.x;
  const long stride = (long)gridDim.x * 256;
  for (; c < total; c += stride) {
    const long row = c >> 7;
    const int ci = (int)(c & 127);
    const int tb = ci >> 2, q = ci & 3;
    const float* base = W + row * HD + tb * 64 + q * 8;
    float4 a0 = *reinterpret_cast<const float4*>(base);
    float4 a1 = *reinterpret_cast<const float4*>(base + 4);
    float4 a2 = *reinterpret_cast<const float4*>(base + 32);
    float4 a3 = *reinterpret_cast<const float4*>(base + 36);
    union { u8 b[16]; uint4 v; } p;
    p.b[0] = f2e4m3(a0.x * WSCALE); p.b[1] = f2e4m3(a0.y * WSCALE);
    p.b[2] = f2e4m3(a0.z * WSCALE); p.b[3] = f2e4m3(a0.w * WSCALE);
    p.b[4] = f2e4m3(a1.x * WSCALE); p.b[5] = f2e4m3(a1.y * WSCALE);
    p.b[6] = f2e4m3(a1.z * WSCALE); p.b[7] = f2e4m3(a1.w * WSCALE);
    p.b[8]  = f2e4m3(a2.x * WSCALE); p.b[9]  = f2e4m3(a2.y * WSCALE);
    p.b[10] = f2e4m3(a2.z * WSCALE); p.b[11] = f2e4m3(a2.w * WSCALE);
    p.b[12] = f2e4m3(a3.x * WSCALE); p.b[13] = f2e4m3(a3.y * WSCALE);
    p.b[14] = f2e4m3(a3.z * WSCALE); p.b[15] = f2e4m3(a3.w * WSCALE);
    reinterpret_cast<uint4*>(w8)[c] = p.v;
  }
}

// ============ 8-wave 256^2 fp8 fused GEMM + softmax partials ============
// Round-10 schedule (reg-dbuf frags, kk-interleave, slot-XOR) shrunk to TWO
// LDS buffers (64 KB + 8 KB epilogue = 72 KB <= 80) -> 2 blocks/CU, 4
// waves/SIMD: block B's MFMAs cover block A's vmcnt/barrier stalls (m114).
// 2-buffer safety (enabled by the register dbuf): buf(T%2)'s last readers
// are the frags(T) reads in body(T-1), retired (lgkm0+sched_barrier) before
// body(T)'s BAR -> STAGE(T+2) into buf(T%2) AFTER the BAR is race-free.
// Body(T): vmcnt(0) [only T+1's 4 loads outstanding] -> BAR -> STAGE(T+2)
// -> RD frags(T+1) overlapping MFMA(T) -> lgkm0+sched_barrier.
__global__ __launch_bounds__(512, 4) void gemm8(
    const u8* __restrict__ x8, const u8* __restrict__ w8,
    float* __restrict__ pmax, float* __restrict__ psum) {
  __shared__ uint4 smem4[4096];                 // 64 KB: 2 bufs x {A 16K, B 16K}
  __shared__ float smax[256][4];
  __shared__ float ssum[256][4];
  char* Sm = reinterpret_cast<char*>(smem4);

  const int tid = threadIdx.x;
  const int w = tid >> 6, l = tid & 63;
  const int wr = w >> 2, wc = w & 3;            // 2M x 4N waves, 128x64 each
  const int q = l >> 4, r15 = l & 15;

  // XCD-bijective swizzle: 8000 = 8 * 1000; mb fast (W panel L2-reuse)
  const int bid = blockIdx.x;
  const int s = (bid & 7) * 1000 + (bid >> 3);
  const int mb = s & (NMB8 - 1);
  const int vb = s >> 4;
  const int rowbase = mb * 256, vbase = vb * 256;

  // -------- staging: 4 calls/tile (A rows 0-127, 128-255; B same) --------
  // call i: lin = i*8192 + tid*16; row = lin>>6; stored slot s_st=(lin>>4)&3
  // holds logical slot qsl = s_st ^ (row&3)  (slot-XOR, conflict-free reads).
  const u8* aS0; const u8* aS1; const u8* bS0; const u8* bS1;
  {
    u32 lin0 = (u32)tid * 16u;
    u32 r0 = lin0 >> 6, q0 = ((lin0 >> 4) & 3u) ^ (r0 & 3u);
    u32 lin1 = 8192u + (u32)tid * 16u;
    u32 r1 = lin1 >> 6, q1 = ((lin1 >> 4) & 3u) ^ (r1 & 3u);
    aS0 = x8 + (size_t)(rowbase + (int)r0) * HD + q0 * 16u;
    aS1 = x8 + (size_t)(rowbase + (int)r1) * HD + q1 * 16u;
    bS0 = w8 + (size_t)(vbase + (int)r0) * HD + q0 * 16u;
    bS1 = w8 + (size_t)(vbase + (int)r1) * HD + q1 * 16u;
  }
  const u32 dA0 = (u32)(w * 1024);
  const u32 dA1 = 8192u + (u32)(w * 1024);
  const u32 dB0 = 16384u + (u32)(w * 1024);
  const u32 dB1 = 24576u + (u32)(w * 1024);

  auto stg = [&](const u8* src, u32 dstOff) {
    __builtin_amdgcn_global_load_lds(
        (const __attribute__((address_space(1))) u32*)src,
        (__attribute__((address_space(3))) u32*)(Sm + dstOff), 16, 0, 0);
  };
#define STAGE(T, OFF) do {                      \
    stg(aS0 + (size_t)(T) * 64, (OFF) + dA0);   \
    stg(aS1 + (size_t)(T) * 64, (OFF) + dA1);   \
    stg(bS0 + (size_t)(T) * 64, (OFF) + dB0);   \
    stg(bS1 + (size_t)(T) * 64, (OFF) + dB1);   \
  } while (0)

  // -------- fragment read bases: one b128 per frag, slot = q^(r15&3) --------
  const u32 slot = ((u32)q ^ ((u32)r15 & 3u)) << 4;
  const u32 aBase = ((u32)(wr * 128 + r15) << 6) + slot;            // + jj*1024
  const u32 bBase = 16384u + ((u32)(wc * 64 + r15) << 6) + slot;    // + nn*1024

  i64x2 s0a[8], s0b[4], s1a[8], s1b[4];
  f32x4 acc[8][4];
#pragma unroll
  for (int m = 0; m < 8; ++m)
#pragma unroll
    for (int n = 0; n < 4; ++n) acc[m][n] = (f32x4)(0.0f);

#define RD_NEXT(NA, NB, RDOFF) do {                                            \
    const char* _p = Sm + (RDOFF);                                             \
    _Pragma("unroll") for (int jj = 0; jj < 8; ++jj)                           \
      NA[jj] = *reinterpret_cast<const i64x2*>(_p + aBase + jj * 1024);        \
    _Pragma("unroll") for (int nn = 0; nn < 4; ++nn)                           \
      NB[nn] = *reinterpret_cast<const i64x2*>(_p + bBase + nn * 1024);        \
  } while (0)

#define MM(CA, CB) do {                                                        \
    __builtin_amdgcn_s_setprio(1);                                             \
    _Pragma("unroll") for (int jj = 0; jj < 8; ++jj)                           \
      _Pragma("unroll") for (int nn = 0; nn < 4; ++nn) {                       \
        acc[jj][nn] = __builtin_amdgcn_mfma_f32_16x16x32_fp8_fp8(              \
            CA[jj][0], CB[nn][0], acc[jj][nn], 0, 0, 0);                       \
        acc[jj][nn] = __builtin_amdgcn_mfma_f32_16x16x32_fp8_fp8(              \
            CA[jj][1], CB[nn][1], acc[jj][nn], 0, 0, 0);                       \
      }                                                                        \
    __builtin_amdgcn_s_setprio(0);                                             \
  } while (0)

// Body(T): vmcnt(0) waits T+1 (the only outstanding loads, issued one body
// ago). BAR then proves (a) T+1 landed from all waves, (b) all waves' frags(T)
// reads retired (their lgkm0 preceded this barrier) -> STAGE(T+2) into
// buf(T%2) is safe.
#define BODY(T, CA, CB, NA, NB, STOFF, RDOFF) do {                             \
    if ((T) + 1 < NT8) {                                                       \
      asm volatile("s_waitcnt vmcnt(0)" ::: "memory");                         \
      __builtin_amdgcn_s_barrier();                                            \
      __builtin_amdgcn_sched_barrier(0);                                       \
      if ((T) + 2 < NT8) { STAGE((T) + 2, STOFF); }                            \
      RD_NEXT(NA, NB, RDOFF);                                                  \
    }                                                                          \
    MM(CA, CB);                                                                \
    asm volatile("s_waitcnt lgkmcnt(0)" ::: "memory");                         \
    __builtin_amdgcn_sched_barrier(0);                                         \
  } while (0)

  // -------- prologue: stage T0 -> buf0, T1 -> buf1; preload frags(T0) --------
  STAGE(0, 0u);
  STAGE(1, 32768u);
  asm volatile("s_waitcnt vmcnt(4)" ::: "memory");
  __builtin_amdgcn_s_barrier();
  __builtin_amdgcn_sched_barrier(0);
  {
    const char* _p = Sm;
#pragma unroll
    for (int jj = 0; jj < 8; ++jj)
      s0a[jj] = *reinterpret_cast<const i64x2*>(_p + aBase + jj * 1024);
#pragma unroll
    for (int nn = 0; nn < 4; ++nn)
      s0b[nn] = *reinterpret_cast<const i64x2*>(_p + bBase + nn * 1024);
  }
  // protect buf0 from body(0)'s STAGE(2): all preload reads must retire first
  asm volatile("s_waitcnt lgkmcnt(0)" ::: "memory");
  __builtin_amdgcn_sched_barrier(0);

  // -------- K-loop: 32 tiles, unrolled x2 (static bufs: even st=0,rd=1) ----
  for (int t = 0; t < NT8; t += 2) {
    BODY(t,     s0a, s0b, s1a, s1b, 0u,      32768u);
    BODY(t + 1, s1a, s1b, s0a, s0b, 32768u,  0u);
  }
#undef BODY
#undef MM
#undef RD_NEXT
#undef STAGE

  // -------- epilogue: unscale, per-row max + sum(exp) over 256 vocab cols ----
  // C/D: col = lane&15, row = (lane>>4)*4 + reg. Wave rows: wr*128+jj*16+q*4+j;
  // wave cols: wc*64 + nn*16 + (lane&15).
#pragma unroll
  for (int jj = 0; jj < 8; ++jj) {
#pragma unroll
    for (int j = 0; j < 4; ++j) {
      float v0 = acc[jj][0][j] * UNSCALE, v1 = acc[jj][1][j] * UNSCALE;
      float v2 = acc[jj][2][j] * UNSCALE, v3 = acc[jj][3][j] * UNSCALE;
      float mx = fmaxf(fmaxf(v0, v1), fmaxf(v2, v3));
#pragma unroll
      for (int d = 1; d < 16; d <<= 1) mx = fmaxf(mx, __shfl_xor(mx, d));
      float se = __expf(v0 - mx) + __expf(v1 - mx) + __expf(v2 - mx) + __expf(v3 - mx);
#pragma unroll
      for (int d = 1; d < 16; d <<= 1) se += __shfl_xor(se, d);
      if (r15 == 0) {
        int r = wr * 128 + jj * 16 + q * 4 + j;
        smax[r][wc] = mx;
        ssum[r][wc] = se;
      }
    }
  }
  __syncthreads();
  if (tid < 256) {
    float m0 = smax[tid][0], m1 = smax[tid][1], m2 = smax[tid][2], m3 = smax[tid][3];
    float M = fmaxf(fmaxf(m0, m1), fmaxf(m2, m3));
    float S = ssum[tid][0] * __expf(m0 - M) + ssum[tid][1] * __expf(m1 - M) +
              ssum[tid][2] * __expf(m2 - M) + ssum[tid][3] * __expf(m3 - M);
    size_t o = (size_t)vb * NR + (size_t)(rowbase + tid);
    pmax[o] = M;
    psum[o] = S;
  }
}

// ================= fallback path (round-1 bf16, proven) =================
__global__ __launch_bounds__(256) void cvt_x_kernel(const float* __restrict__ x,
                                                    u16* __restrict__ xb) {
  int i = blockIdx.x * 256 + threadIdx.x;
  float4 v = reinterpret_cast<const float4*>(x)[i];
  union { __bf16 b[4]; unsigned long long ll; } p;
  p.b[0] = (__bf16)v.x; p.b[1] = (__bf16)v.y;
  p.b[2] = (__bf16)v.z; p.b[3] = (__bf16)v.w;
  reinterpret_cast<unsigned long long*>(xb)[i] = p.ll;
}

__global__ __launch_bounds__(256) void gemm_partials_fb(
    const u16* __restrict__ xb, const float* __restrict__ W,
    float* __restrict__ pmax, float* __restrict__ psum) {
  __shared__ uint4 smem[1024];
  __shared__ float smax[128][2];
  __shared__ float ssum[128][2];
  char* Ab = reinterpret_cast<char*>(smem);
  char* Bb = Ab + 8192;

  const int tid = threadIdx.x;
  const int w = tid >> 6;
  const int l = tid & 63;
  const int wr = w >> 1, wc = w & 1;

  const int bid = blockIdx.x;
  const int s = (bid & 7) * (NMBF * NVBF / 8) + (bid >> 3);
  const int mb = s & (NMBF - 1);
  const int vb = s >> 5;
  const int rowbase = mb * 128;
  const int vbase = vb * 128;

  const u16* aSrc[2];
  unsigned aBase[2];
#pragma unroll
  for (int i = 0; i < 2; ++i) {
    unsigned lin = (unsigned)w * 2048u + (unsigned)i * 1024u + (unsigned)l * 16u;
    unsigned sb = swz16(lin);
    unsigned r = sb >> 6;
    unsigned c = (sb >> 1) & 31u;
    aSrc[i] = xb + (size_t)(rowbase + (int)r) * HD + c;
    aBase[i] = (unsigned)w * 2048u + (unsigned)i * 1024u;
  }
  const float* bSrc[2];
  unsigned bLin[2];
#pragma unroll
  for (int i = 0; i < 2; ++i) {
    unsigned lin = (unsigned)i * 4096u + (unsigned)tid * 16u;
    unsigned sb = swz16(lin);
    unsigned n = sb >> 6;
    unsigned k = (sb >> 1) & 31u;
    bSrc[i] = W + (size_t)(vbase + (int)n) * HD + k;
    bLin[i] = lin;
  }
  const unsigned q = (unsigned)(l >> 4);
  unsigned aOff[4], bOff[4];
#pragma unroll
  for (int m = 0; m < 4; ++m) {
    unsigned R = (unsigned)(wr * 64 + m * 16 + (l & 15));
    aOff[m] = swz16(R * 64u + q * 16u);
    R = (unsigned)(wc * 64 + m * 16 + (l & 15));
    bOff[m] = swz16(R * 64u + q * 16u);
  }
  f32x4 acc[4][4];
#pragma unroll
  for (int m = 0; m < 4; ++m)
#pragma unroll
    for (int n = 0; n < 4; ++n) acc[m][n] = (f32x4)(0.0f);

  for (int kt = 0; kt < HD; kt += 32) {
    float4 g0 = *reinterpret_cast<const float4*>(bSrc[0]);
    float4 g1 = *reinterpret_cast<const float4*>(bSrc[0] + 4);
    float4 g2 = *reinterpret_cast<const float4*>(bSrc[1]);
    float4 g3 = *reinterpret_cast<const float4*>(bSrc[1] + 4);
#pragma unroll
    for (int i = 0; i < 2; ++i) {
      __builtin_amdgcn_global_load_lds(
          (const __attribute__((address_space(1))) u32*)aSrc[i],
          (__attribute__((address_space(3))) u32*)(Ab + aBase[i]), 16, 0, 0);
    }
    union { __bf16 b[8]; uint4 v; } p0, p1;
    p0.b[0] = (__bf16)g0.x; p0.b[1] = (__bf16)g0.y; p0.b[2] = (__bf16)g0.z; p0.b[3] = (__bf16)g0.w;
    p0.b[4] = (__bf16)g1.x; p0.b[5] = (__bf16)g1.y; p0.b[6] = (__bf16)g1.z; p0.b[7] = (__bf16)g1.w;
    p1.b[0] = (__bf16)g2.x; p1.b[1] = (__bf16)g2.y; p1.b[2] = (__bf16)g2.z; p1.b[3] = (__bf16)g2.w;
    p1.b[4] = (__bf16)g3.x; p1.b[5] = (__bf16)g3.y; p1.b[6] = (__bf16)g3.z; p1.b[7] = (__bf16)g3.w;
    *reinterpret_cast<uint4*>(Bb + bLin[0]) = p0.v;
    *reinterpret_cast<uint4*>(Bb + bLin[1]) = p1.v;
    __syncthreads();

    short8 af[4], bfr[4];
#pragma unroll
    for (int m = 0; m < 4; ++m) af[m] = *reinterpret_cast<const short8*>(Ab + aOff[m]);
#pragma unroll
    for (int n = 0; n < 4; ++n) bfr[n] = *reinterpret_cast<const short8*>(Bb + bOff[n]);
#pragma unroll
    for (int m = 0; m < 4; ++m)
#pragma unroll
      for (int n = 0; n < 4; ++n)
        acc[m][n] = __builtin_amdgcn_mfma_f32_16x16x32_bf16(af[m], bfr[n], acc[m][n], 0, 0, 0);
    __syncthreads();

    aSrc[0] += 32; aSrc[1] += 32;
    bSrc[0] += 32; bSrc[1] += 32;
  }
#pragma unroll
  for (int m = 0; m < 4; ++m) {
#pragma unroll
    for (int j = 0; j < 4; ++j) {
      float v0 = acc[m][0][j], v1 = acc[m][1][j], v2 = acc[m][2][j], v3 = acc[m][3][j];
      float mx = fmaxf(fmaxf(v0, v1), fmaxf(v2, v3));
#pragma unroll
      for (int d = 1; d < 16; d <<= 1) mx = fmaxf(mx, __shfl_xor(mx, d));
      float se = __expf(v0 - mx) + __expf(v1 - mx) + __expf(v2 - mx) + __expf(v3 - mx);
#pragma unroll
      for (int d = 1; d < 16; d <<= 1) se += __shfl_xor(se, d);
      if ((l & 15) == 0) {
        int rloc = wr * 64 + m * 16 + (int)q * 4 + j;
        smax[rloc][wc] = mx;
        ssum[rloc][wc] = se;
      }
    }
  }
  __syncthreads();
  if (tid < 128) {
    float m0 = smax[tid][0], m1 = smax[tid][1];
    float M = fmaxf(m0, m1);
    float S = ssum[tid][0] * __expf(m0 - M) + ssum[tid][1] * __expf(m1 - M);
    size_t o = (size_t)vb * NR + (size_t)(rowbase + tid);
    pmax[o] = M;
    psum[o] = S;
  }
}

// ---------------- merge partials -> LSE per row ----------------
__global__ __launch_bounds__(256) void row_lse_kernel(const float* __restrict__ pmax,
                                                      const float* __restrict__ psum,
                                                      float* __restrict__ lse, int nvb) {
  __shared__ float lm[4][64];
  __shared__ float ls[4][64];
  const int rb = blockIdx.x * 64;
  const int rl = threadIdx.x & 63;
  const int g = threadIdx.x >> 6;
  const int r = rb + rl;
  float M = -3.0e38f, S = 0.0f;
  for (int v = g; v < nvb; v += 4) {
    float m = pmax[(size_t)v * NR + r];
    float s = psum[(size_t)v * NR + r];
    float nM = fmaxf(M, m);
    S = S * __expf(M - nM) + s * __expf(m - nM);
    M = nM;
  }
  lm[g][rl] = M; ls[g][rl] = S;
  __syncthreads();
  if (threadIdx.x < 64) {
    float M0 = lm[0][rl], S0 = ls[0][rl];
#pragma unroll
    for (int g2 = 1; g2 < 4; ++g2) {
      float m = lm[g2][rl], s2 = ls[g2][rl];
      float nM = fmaxf(M0, m);
      S0 = S0 * __expf(M0 - nM) + s2 * __expf(m - nM);
      M0 = nM;
    }
    lse[r] = M0 + logf(S0);
  }
}

// ---------------- target logit: dot(x[n], W[y[n]]) in f32 (exact) ----------------
__global__ __launch_bounds__(256) void tlogit_kernel(const float* __restrict__ x,
                                                     const int* __restrict__ y,
                                                     const float* __restrict__ W,
                                                     float* __restrict__ tl) {
  const int row = blockIdx.x * 4 + (threadIdx.x >> 6);
  const int l = threadIdx.x & 63;
  const int t = y[row];
  const float4* xr = reinterpret_cast<const float4*>(x + (size_t)row * HD);
  const float4* wr = reinterpret_cast<const float4*>(W + (size_t)t * HD);
  float s = 0.0f;
#pragma unroll
  for (int i = 0; i < HD / 4 / 64; ++i) {
    float4 a = xr[l + i * 64];
    float4 b = wr[l + i * 64];
    s += a.x * b.x + a.y * b.y + a.z * b.z + a.w * b.w;
  }
#pragma unroll
  for (int d = 1; d < 64; d <<= 1) s += __shfl_xor(s, d);
  if (l == 0) tl[row] = s;
}

// ---------------- mean(lse - tlogit) ----------------
__global__ __launch_bounds__(256) void finalize_kernel(const float* __restrict__ lse,
                                                       const float* __restrict__ tl,
                                                       float* __restrict__ out) {
  __shared__ float red[256];
  float s = 0.0f;
  for (int i = threadIdx.x; i < NR; i += 256) s += lse[i] - tl[i];
  red[threadIdx.x] = s;
  __syncthreads();
  for (int d = 128; d > 0; d >>= 1) {
    if ((int)threadIdx.x < d) red[threadIdx.x] += red[threadIdx.x + d];
    __syncthreads();
  }
  if (threadIdx.x == 0) out[0] = red[0] * (1.0f / NR);
}

extern "C" void kernel_launch(void* const* d_in, const int* in_sizes, int n_in,
                              void* d_out, int out_size, void* d_ws, size_t ws_size,
                              hipStream_t stream) {
  const float* x = (const float*)d_in[0];
  const int* y = (const int*)d_in[1];
  const float* W = (const float*)d_in[2];
  float* out = (float*)d_out;
  char* ws = (char*)d_ws;

  if (ws_size >= NEED_NEW) {
    u8* x8      = (u8*)(ws + OFF_X8);
    u8* w8      = (u8*)(ws + OFF_W8);
    float* pmax = (float*)(ws + OFF_PMX);
    float* psum = (float*)(ws + OFF_PSM);
    float* lse  = (float*)(ws + OFF_LSE);
    float* tl   = (float*)(ws + OFF_TL);
    cvt_x8_kernel<<<NR * HD / 16 / 256, 256, 0, stream>>>(x, x8);
    cvt_w8_kernel<<<4096, 256, 0, stream>>>(W, w8);
    gemm8<<<NMB8 * NVB8, 512, 0, stream>>>(x8, w8, pmax, psum);
    row_lse_kernel<<<NR / 64, 256, 0, stream>>>(pmax, psum, lse, NVB8);
    tlogit_kernel<<<NR / 4, 256, 0, stream>>>(x, y, W, tl);
    finalize_kernel<<<1, 256, 0, stream>>>(lse, tl, out);
  } else {
    u16* xb     = (u16*)(ws + FB_XB);
    float* pmax = (float*)(ws + FB_PMAX);
    float* psum = (float*)(ws + FB_PSUM);
    float* lse  = (float*)(ws + FB_LSE);
    float* tl   = (float*)(ws + FB_TL);
    cvt_x_kernel<<<NR * HD / 4 / 256, 256, 0, stream>>>(x, xb);
    gemm_partials_fb<<<NMBF * NVBF, 256, 0, stream>>>(xb, W, pmax, psum);
    row_lse_kernel<<<NR / 64, 256, 0, stream>>>(pmax, psum, lse, NVBF);
    tlogit_kernel<<<NR / 4, 256, 0, stream>>>(x, y, W, tl);
    finalize_kernel<<<1, 256, 0, stream>>>(lse, tl, out);
  }
}

// Round 12
// 2001.652 us; speedup vs baseline: 8.8436x; 8.8436x over previous
//
#include <hip/hip_runtime.h>
#include <hip/hip_fp8.h>

typedef unsigned short u16;
typedef unsigned char u8;
typedef unsigned int u32;
typedef long long i64;
typedef __attribute__((ext_vector_type(2))) i64 i64x2;
typedef __attribute__((ext_vector_type(8))) short short8;
typedef __attribute__((ext_vector_type(4))) float f32x4;

constexpr int HD = 2048;     // hidden / K (bytes in fp8)
constexpr int NR = 4096;     // rows B*S
constexpr int VO = 128000;   // vocab

// ---------------- fp8 path geometry: 256^2 tile, K-tile = 64 B ----------------
constexpr int NMB8 = NR / 256;    // 16
constexpr int NVB8 = VO / 256;    // 500
constexpr int NT8  = HD / 64;     // 32 K-tiles
constexpr float XSCALE = 32.0f;
constexpr float WSCALE = 16384.0f;
constexpr float UNSCALE = 1.0f / (XSCALE * WSCALE);

// ws layout (fp8 path)
constexpr size_t OFF_X8  = 0;                          // 8,388,608
constexpr size_t OFF_W8  = 8388608;                    // 262,144,000
constexpr size_t OFF_PMX = OFF_W8 + 262144000;         // 8,192,000
constexpr size_t OFF_PSM = OFF_PMX + 8192000;
constexpr size_t OFF_LSE = OFF_PSM + 8192000;
constexpr size_t OFF_TL  = OFF_LSE + 16384;
constexpr size_t NEED_NEW = OFF_TL + 16384;            // ~287 MB

// ws layout, fallback (round-1 bf16 128^2, proven)
constexpr int NVBF = VO / 128;
constexpr int NMBF = NR / 128;
constexpr size_t FB_XB   = 0;
constexpr size_t FB_PMAX = 16777216;
constexpr size_t FB_PSUM = FB_PMAX + 16384000;
constexpr size_t FB_LSE  = FB_PSUM + 16384000;
constexpr size_t FB_TL   = FB_LSE + (size_t)NR * 4;

// fallback swizzle
__device__ __forceinline__ u32 swz16(u32 a) { return a ^ (((a >> 7) & 3u) << 4); }

__device__ __forceinline__ u8 f2e4m3(float f) {
  return (u8)__hip_cvt_float_to_fp8(f, __HIP_SATFINITE, __HIP_E4M3);
}

// ---------------- x f32 -> fp8, kk-interleaved layout ----------------
// Per row, per 64B K-block: cell q (16B) holds elements k = kk*32 + q*8 + b
// at byte kk*8+b. One 16B LDS cell = a lane's full K=64 operand (both kk
// halves) -> single ds_read_b128 per fragment.
__global__ __launch_bounds__(256) void cvt_x8_kernel(const float* __restrict__ x,
                                                     u8* __restrict__ x8) {
  const long c = (long)blockIdx.x * 256 + threadIdx.x;   // 16B cell index
  const long row = c >> 7;                                // 128 cells/row
  const int ci = (int)(c & 127);
  const int tb = ci >> 2, q = ci & 3;
  const float* base = x + row * HD + tb * 64 + q * 8;
  float4 a0 = *reinterpret_cast<const float4*>(base);
  float4 a1 = *reinterpret_cast<const float4*>(base + 4);
  float4 a2 = *reinterpret_cast<const float4*>(base + 32);
  float4 a3 = *reinterpret_cast<const float4*>(base + 36);
  union { u8 b[16]; uint4 v; } p;
  p.b[0] = f2e4m3(a0.x * XSCALE); p.b[1] = f2e4m3(a0.y * XSCALE);
  p.b[2] = f2e4m3(a0.z * XSCALE); p.b[3] = f2e4m3(a0.w * XSCALE);
  p.b[4] = f2e4m3(a1.x * XSCALE); p.b[5] = f2e4m3(a1.y * XSCALE);
  p.b[6] = f2e4m3(a1.z * XSCALE); p.b[7] = f2e4m3(a1.w * XSCALE);
  p.b[8]  = f2e4m3(a2.x * XSCALE); p.b[9]  = f2e4m3(a2.y * XSCALE);
  p.b[10] = f2e4m3(a2.z * XSCALE); p.b[11] = f2e4m3(a2.w * XSCALE);
  p.b[12] = f2e4m3(a3.x * XSCALE); p.b[13] = f2e4m3(a3.y * XSCALE);
  p.b[14] = f2e4m3(a3.z * XSCALE); p.b[15] = f2e4m3(a3.w * XSCALE);
  reinterpret_cast<uint4*>(x8)[c] = p.v;
}

// ---------------- W f32 -> fp8, same kk-interleaved layout ----------------
__global__ __launch_bounds__(256) void cvt_w8_kernel(const float* __restrict__ W,
                                                     u8* __restrict__ w8) {
  const long total = (long)VO * HD / 16;                 // cells
  long c = (long)blockIdx.x * 256 + threadIdx.x;
  const long stride = (long)gridDim.x * 256;
  for (; c < total; c += stride) {
    const long row = c >> 7;
    const int ci = (int)(c & 127);
    const int tb = ci >> 2, q = ci & 3;
    const float* base = W + row * HD + tb * 64 + q * 8;
    float4 a0 = *reinterpret_cast<const float4*>(base);
    float4 a1 = *reinterpret_cast<const float4*>(base + 4);
    float4 a2 = *reinterpret_cast<const float4*>(base + 32);
    float4 a3 = *reinterpret_cast<const float4*>(base + 36);
    union { u8 b[16]; uint4 v; } p;
    p.b[0] = f2e4m3(a0.x * WSCALE); p.b[1] = f2e4m3(a0.y * WSCALE);
    p.b[2] = f2e4m3(a0.z * WSCALE); p.b[3] = f2e4m3(a0.w * WSCALE);
    p.b[4] = f2e4m3(a1.x * WSCALE); p.b[5] = f2e4m3(a1.y * WSCALE);
    p.b[6] = f2e4m3(a1.z * WSCALE); p.b[7] = f2e4m3(a1.w * WSCALE);
    p.b[8]  = f2e4m3(a2.x * WSCALE); p.b[9]  = f2e4m3(a2.y * WSCALE);
    p.b[10] = f2e4m3(a2.z * WSCALE); p.b[11] = f2e4m3(a2.w * WSCALE);
    p.b[12] = f2e4m3(a3.x * WSCALE); p.b[13] = f2e4m3(a3.y * WSCALE);
    p.b[14] = f2e4m3(a3.z * WSCALE); p.b[15] = f2e4m3(a3.w * WSCALE);
    reinterpret_cast<uint4*>(w8)[c] = p.v;
  }
}

// ============ 8-wave 256^2 fp8 fused GEMM + softmax partials ============
// Round-10 geometry (512 threads @ (512,2): 2M x 4N waves of 128x64, acc
// 128 AGPR + reg-dbuf frags 96 VGPR in the 256-reg class, NO spill —
// round-11 lesson: min-waves 4 would cap regs at 128 and spill 90 GB) +
// round-9 3-buffer schedule (regs already cap us at 1 block/CU, so 96 KB
// LDS is free). Body(T): STAGE(T+2)->buf((T+2)%3) issued FIRST, then
// counted vmcnt(4) (waits T+1's 4 loads issued two bodies ago; ignores the
// 4 just issued) -> BAR -> RD frags(T+1) overlapping MFMA frags(T) ->
// lgkm0+sched_barrier.
// Safety: buf((T+2)%3)'s last readers were frags(T-1) reads in body(T-2),
// retired before that body's lgkm0 which precedes BAR(T-1); any wave
// issuing STAGE(T+2) is past BAR(T-1) -> no race. Prologue case: body(1)
// stages buf0, whose preload-frag readers retired before BAR(body 0).
__global__ __launch_bounds__(512, 2) void gemm8(
    const u8* __restrict__ x8, const u8* __restrict__ w8,
    float* __restrict__ pmax, float* __restrict__ psum) {
  __shared__ uint4 smem4[6144];                 // 96 KB: 3 bufs x {A 16K, B 16K}
  __shared__ float smax[256][4];
  __shared__ float ssum[256][4];
  char* Sm = reinterpret_cast<char*>(smem4);

  const int tid = threadIdx.x;
  const int w = tid >> 6, l = tid & 63;
  const int wr = w >> 2, wc = w & 3;            // 2M x 4N waves, 128x64 each
  const int q = l >> 4, r15 = l & 15;

  // XCD-bijective swizzle: 8000 = 8 * 1000; mb fast (W panel L2-reuse)
  const int bid = blockIdx.x;
  const int s = (bid & 7) * 1000 + (bid >> 3);
  const int mb = s & (NMB8 - 1);
  const int vb = s >> 4;
  const int rowbase = mb * 256, vbase = vb * 256;

  // -------- staging: 4 calls/tile (A rows 0-127, 128-255; B same) --------
  // call i: lin = i*8192 + tid*16; row = lin>>6; stored slot s_st=(lin>>4)&3
  // holds logical slot qsl = s_st ^ (row&3)  (slot-XOR, conflict-free reads).
  const u8* aS0; const u8* aS1; const u8* bS0; const u8* bS1;
  {
    u32 lin0 = (u32)tid * 16u;
    u32 r0 = lin0 >> 6, q0 = ((lin0 >> 4) & 3u) ^ (r0 & 3u);
    u32 lin1 = 8192u + (u32)tid * 16u;
    u32 r1 = lin1 >> 6, q1 = ((lin1 >> 4) & 3u) ^ (r1 & 3u);
    aS0 = x8 + (size_t)(rowbase + (int)r0) * HD + q0 * 16u;
    aS1 = x8 + (size_t)(rowbase + (int)r1) * HD + q1 * 16u;
    bS0 = w8 + (size_t)(vbase + (int)r0) * HD + q0 * 16u;
    bS1 = w8 + (size_t)(vbase + (int)r1) * HD + q1 * 16u;
  }
  const u32 dA0 = (u32)(w * 1024);
  const u32 dA1 = 8192u + (u32)(w * 1024);
  const u32 dB0 = 16384u + (u32)(w * 1024);
  const u32 dB1 = 24576u + (u32)(w * 1024);

  auto stg = [&](const u8* src, u32 dstOff) {
    __builtin_amdgcn_global_load_lds(
        (const __attribute__((address_space(1))) u32*)src,
        (__attribute__((address_space(3))) u32*)(Sm + dstOff), 16, 0, 0);
  };
#define STAGE(T, OFF) do {                      \
    stg(aS0 + (size_t)(T) * 64, (OFF) + dA0);   \
    stg(aS1 + (size_t)(T) * 64, (OFF) + dA1);   \
    stg(bS0 + (size_t)(T) * 64, (OFF) + dB0);   \
    stg(bS1 + (size_t)(T) * 64, (OFF) + dB1);   \
  } while (0)

  // -------- fragment read bases: one b128 per frag, slot = q^(r15&3) --------
  const u32 slot = ((u32)q ^ ((u32)r15 & 3u)) << 4;
  const u32 aBase = ((u32)(wr * 128 + r15) << 6) + slot;            // + jj*1024
  const u32 bBase = 16384u + ((u32)(wc * 64 + r15) << 6) + slot;    // + nn*1024

  i64x2 s0a[8], s0b[4], s1a[8], s1b[4];
  f32x4 acc[8][4];
#pragma unroll
  for (int m = 0; m < 8; ++m)
#pragma unroll
    for (int n = 0; n < 4; ++n) acc[m][n] = (f32x4)(0.0f);

#define RD_NEXT(NA, NB, RDOFF) do {                                            \
    const char* _p = Sm + (RDOFF);                                             \
    _Pragma("unroll") for (int jj = 0; jj < 8; ++jj)                           \
      NA[jj] = *reinterpret_cast<const i64x2*>(_p + aBase + jj * 1024);        \
    _Pragma("unroll") for (int nn = 0; nn < 4; ++nn)                           \
      NB[nn] = *reinterpret_cast<const i64x2*>(_p + bBase + nn * 1024);        \
  } while (0)

#define MM(CA, CB) do {                                                        \
    __builtin_amdgcn_s_setprio(1);                                             \
    _Pragma("unroll") for (int jj = 0; jj < 8; ++jj)                           \
      _Pragma("unroll") for (int nn = 0; nn < 4; ++nn) {                       \
        acc[jj][nn] = __builtin_amdgcn_mfma_f32_16x16x32_fp8_fp8(              \
            CA[jj][0], CB[nn][0], acc[jj][nn], 0, 0, 0);                       \
        acc[jj][nn] = __builtin_amdgcn_mfma_f32_16x16x32_fp8_fp8(              \
            CA[jj][1], CB[nn][1], acc[jj][nn], 0, 0, 0);                       \
      }                                                                        \
    __builtin_amdgcn_s_setprio(0);                                             \
  } while (0)

// Body(T): STAGE(T+2) first (into the buffer retired two barriers ago), then
// vmcnt(4) = "tile T+1 landed" (outstanding: T+1's 4 + T+2's 4 = 8; waiting
// to 4 drains the oldest 4 = T+1). Tail: T=NT8-2 has no stage -> vmcnt(0)
// waits T+1 alone; T=NT8-1 skips wait/BAR/RD entirely.
#define BODY(T, CA, CB, NA, NB) do {                                           \
    if ((T) + 2 < NT8) { STAGE((T) + 2, stOff); }                              \
    if ((T) + 1 < NT8) {                                                       \
      if ((T) + 2 < NT8) asm volatile("s_waitcnt vmcnt(4)" ::: "memory");      \
      else               asm volatile("s_waitcnt vmcnt(0)" ::: "memory");      \
      __builtin_amdgcn_s_barrier();                                            \
      __builtin_amdgcn_sched_barrier(0);                                       \
      RD_NEXT(NA, NB, rdOff);                                                  \
    }                                                                          \
    MM(CA, CB);                                                                \
    asm volatile("s_waitcnt lgkmcnt(0)" ::: "memory");                         \
    __builtin_amdgcn_sched_barrier(0);                                         \
    rdOff = (rdOff == 65536u) ? 0u : rdOff + 32768u;                           \
    stOff = (stOff == 65536u) ? 0u : stOff + 32768u;                           \
  } while (0)

  // -------- prologue: stage T0 -> buf0, T1 -> buf1; preload frags(T0) --------
  STAGE(0, 0u);
  STAGE(1, 32768u);
  asm volatile("s_waitcnt vmcnt(4)" ::: "memory");
  __builtin_amdgcn_s_barrier();
  __builtin_amdgcn_sched_barrier(0);
  {
    const char* _p = Sm;
#pragma unroll
    for (int jj = 0; jj < 8; ++jj)
      s0a[jj] = *reinterpret_cast<const i64x2*>(_p + aBase + jj * 1024);
#pragma unroll
    for (int nn = 0; nn < 4; ++nn)
      s0b[nn] = *reinterpret_cast<const i64x2*>(_p + bBase + nn * 1024);
  }
  // retire preload reads of buf0 before body(1) can stage into it
  asm volatile("s_waitcnt lgkmcnt(0)" ::: "memory");
  __builtin_amdgcn_sched_barrier(0);

  u32 rdOff = 32768u;                           // body(0) reads T1 from buf1
  u32 stOff = 65536u;                           // body(0) stages T2 -> buf2

  // -------- K-loop: 32 tiles, unrolled x2 for static frag-set alternation ----
  for (int t = 0; t < NT8; t += 2) {
    BODY(t,     s0a, s0b, s1a, s1b);
    BODY(t + 1, s1a, s1b, s0a, s0b);
  }
#undef BODY
#undef MM
#undef RD_NEXT
#undef STAGE

  // -------- epilogue: unscale, per-row max + sum(exp) over 256 vocab cols ----
  // C/D: col = lane&15, row = (lane>>4)*4 + reg. Wave rows: wr*128+jj*16+q*4+j;
  // wave cols: wc*64 + nn*16 + (lane&15).
#pragma unroll
  for (int jj = 0; jj < 8; ++jj) {
#pragma unroll
    for (int j = 0; j < 4; ++j) {
      float v0 = acc[jj][0][j] * UNSCALE, v1 = acc[jj][1][j] * UNSCALE;
      float v2 = acc[jj][2][j] * UNSCALE, v3 = acc[jj][3][j] * UNSCALE;
      float mx = fmaxf(fmaxf(v0, v1), fmaxf(v2, v3));
#pragma unroll
      for (int d = 1; d < 16; d <<= 1) mx = fmaxf(mx, __shfl_xor(mx, d));
      float se = __expf(v0 - mx) + __expf(v1 - mx) + __expf(v2 - mx) + __expf(v3 - mx);
#pragma unroll
      for (int d = 1; d < 16; d <<= 1) se += __shfl_xor(se, d);
      if (r15 == 0) {
        int r = wr * 128 + jj * 16 + q * 4 + j;
        smax[r][wc] = mx;
        ssum[r][wc] = se;
      }
    }
  }
  __syncthreads();
  if (tid < 256) {
    float m0 = smax[tid][0], m1 = smax[tid][1], m2 = smax[tid][2], m3 = smax[tid][3];
    float M = fmaxf(fmaxf(m0, m1), fmaxf(m2, m3));
    float S = ssum[tid][0] * __expf(m0 - M) + ssum[tid][1] * __expf(m1 - M) +
              ssum[tid][2] * __expf(m2 - M) + ssum[tid][3] * __expf(m3 - M);
    size_t o = (size_t)vb * NR + (size_t)(rowbase + tid);
    pmax[o] = M;
    psum[o] = S;
  }
}

// ================= fallback path (round-1 bf16, proven) =================
__global__ __launch_bounds__(256) void cvt_x_kernel(const float* __restrict__ x,
                                                    u16* __restrict__ xb) {
  int i = blockIdx.x * 256 + threadIdx.x;
  float4 v = reinterpret_cast<const float4*>(x)[i];
  union { __bf16 b[4]; unsigned long long ll; } p;
  p.b[0] = (__bf16)v.x; p.b[1] = (__bf16)v.y;
  p.b[2] = (__bf16)v.z; p.b[3] = (__bf16)v.w;
  reinterpret_cast<unsigned long long*>(xb)[i] = p.ll;
}

__global__ __launch_bounds__(256) void gemm_partials_fb(
    const u16* __restrict__ xb, const float* __restrict__ W,
    float* __restrict__ pmax, float* __restrict__ psum) {
  __shared__ uint4 smem[1024];
  __shared__ float smax[128][2];
  __shared__ float ssum[128][2];
  char* Ab = reinterpret_cast<char*>(smem);
  char* Bb = Ab + 8192;

  const int tid = threadIdx.x;
  const int w = tid >> 6;
  const int l = tid & 63;
  const int wr = w >> 1, wc = w & 1;

  const int bid = blockIdx.x;
  const int s = (bid & 7) * (NMBF * NVBF / 8) + (bid >> 3);
  const int mb = s & (NMBF - 1);
  const int vb = s >> 5;
  const int rowbase = mb * 128;
  const int vbase = vb * 128;

  const u16* aSrc[2];
  unsigned aBase[2];
#pragma unroll
  for (int i = 0; i < 2; ++i) {
    unsigned lin = (unsigned)w * 2048u + (unsigned)i * 1024u + (unsigned)l * 16u;
    unsigned sb = swz16(lin);
    unsigned r = sb >> 6;
    unsigned c = (sb >> 1) & 31u;
    aSrc[i] = xb + (size_t)(rowbase + (int)r) * HD + c;
    aBase[i] = (unsigned)w * 2048u + (unsigned)i * 1024u;
  }
  const float* bSrc[2];
  unsigned bLin[2];
#pragma unroll
  for (int i = 0; i < 2; ++i) {
    unsigned lin = (unsigned)i * 4096u + (unsigned)tid * 16u;
    unsigned sb = swz16(lin);
    unsigned n = sb >> 6;
    unsigned k = (sb >> 1) & 31u;
    bSrc[i] = W + (size_t)(vbase + (int)n) * HD + k;
    bLin[i] = lin;
  }
  const unsigned q = (unsigned)(l >> 4);
  unsigned aOff[4], bOff[4];
#pragma unroll
  for (int m = 0; m < 4; ++m) {
    unsigned R = (unsigned)(wr * 64 + m * 16 + (l & 15));
    aOff[m] = swz16(R * 64u + q * 16u);
    R = (unsigned)(wc * 64 + m * 16 + (l & 15));
    bOff[m] = swz16(R * 64u + q * 16u);
  }
  f32x4 acc[4][4];
#pragma unroll
  for (int m = 0; m < 4; ++m)
#pragma unroll
    for (int n = 0; n < 4; ++n) acc[m][n] = (f32x4)(0.0f);

  for (int kt = 0; kt < HD; kt += 32) {
    float4 g0 = *reinterpret_cast<const float4*>(bSrc[0]);
    float4 g1 = *reinterpret_cast<const float4*>(bSrc[0] + 4);
    float4 g2 = *reinterpret_cast<const float4*>(bSrc[1]);
    float4 g3 = *reinterpret_cast<const float4*>(bSrc[1] + 4);
#pragma unroll
    for (int i = 0; i < 2; ++i) {
      __builtin_amdgcn_global_load_lds(
          (const __attribute__((address_space(1))) u32*)aSrc[i],
          (__attribute__((address_space(3))) u32*)(Ab + aBase[i]), 16, 0, 0);
    }
    union { __bf16 b[8]; uint4 v; } p0, p1;
    p0.b[0] = (__bf16)g0.x; p0.b[1] = (__bf16)g0.y; p0.b[2] = (__bf16)g0.z; p0.b[3] = (__bf16)g0.w;
    p0.b[4] = (__bf16)g1.x; p0.b[5] = (__bf16)g1.y; p0.b[6] = (__bf16)g1.z; p0.b[7] = (__bf16)g1.w;
    p1.b[0] = (__bf16)g2.x; p1.b[1] = (__bf16)g2.y; p1.b[2] = (__bf16)g2.z; p1.b[3] = (__bf16)g2.w;
    p1.b[4] = (__bf16)g3.x; p1.b[5] = (__bf16)g3.y; p1.b[6] = (__bf16)g3.z; p1.b[7] = (__bf16)g3.w;
    *reinterpret_cast<uint4*>(Bb + bLin[0]) = p0.v;
    *reinterpret_cast<uint4*>(Bb + bLin[1]) = p1.v;
    __syncthreads();

    short8 af[4], bfr[4];
#pragma unroll
    for (int m = 0; m < 4; ++m) af[m] = *reinterpret_cast<const short8*>(Ab + aOff[m]);
#pragma unroll
    for (int n = 0; n < 4; ++n) bfr[n] = *reinterpret_cast<const short8*>(Bb + bOff[n]);
#pragma unroll
    for (int m = 0; m < 4; ++m)
#pragma unroll
      for (int n = 0; n < 4; ++n)
        acc[m][n] = __builtin_amdgcn_mfma_f32_16x16x32_bf16(af[m], bfr[n], acc[m][n], 0, 0, 0);
    __syncthreads();

    aSrc[0] += 32; aSrc[1] += 32;
    bSrc[0] += 32; bSrc[1] += 32;
  }
#pragma unroll
  for (int m = 0; m < 4; ++m) {
#pragma unroll
    for (int j = 0; j < 4; ++j) {
      float v0 = acc[m][0][j], v1 = acc[m][1][j], v2 = acc[m][2][j], v3 = acc[m][3][j];
      float mx = fmaxf(fmaxf(v0, v1), fmaxf(v2, v3));
#pragma unroll
      for (int d = 1; d < 16; d <<= 1) mx = fmaxf(mx, __shfl_xor(mx, d));
      float se = __expf(v0 - mx) + __expf(v1 - mx) + __expf(v2 - mx) + __expf(v3 - mx);
#pragma unroll
      for (int d = 1; d < 16; d <<= 1) se += __shfl_xor(se, d);
      if ((l & 15) == 0) {
        int rloc = wr * 64 + m * 16 + (int)q * 4 + j;
        smax[rloc][wc] = mx;
        ssum[rloc][wc] = se;
      }
    }
  }
  __syncthreads();
  if (tid < 128) {
    float m0 = smax[tid][0], m1 = smax[tid][1];
    float M = fmaxf(m0, m1);
    float S = ssum[tid][0] * __expf(m0 - M) + ssum[tid][1] * __expf(m1 - M);
    size_t o = (size_t)vb * NR + (size_t)(rowbase + tid);
    pmax[o] = M;
    psum[o] = S;
  }
}

// ---------------- merge partials -> LSE per row ----------------
__global__ __launch_bounds__(256) void row_lse_kernel(const float* __restrict__ pmax,
                                                      const float* __restrict__ psum,
                                                      float* __restrict__ lse, int nvb) {
  __shared__ float lm[4][64];
  __shared__ float ls[4][64];
  const int rb = blockIdx.x * 64;
  const int rl = threadIdx.x & 63;
  const int g = threadIdx.x >> 6;
  const int r = rb + rl;
  float M = -3.0e38f, S = 0.0f;
  for (int v = g; v < nvb; v += 4) {
    float m = pmax[(size_t)v * NR + r];
    float s = psum[(size_t)v * NR + r];
    float nM = fmaxf(M, m);
    S = S * __expf(M - nM) + s * __expf(m - nM);
    M = nM;
  }
  lm[g][rl] = M; ls[g][rl] = S;
  __syncthreads();
  if (threadIdx.x < 64) {
    float M0 = lm[0][rl], S0 = ls[0][rl];
#pragma unroll
    for (int g2 = 1; g2 < 4; ++g2) {
      float m = lm[g2][rl], s2 = ls[g2][rl];
      float nM = fmaxf(M0, m);
      S0 = S0 * __expf(M0 - nM) + s2 * __expf(m - nM);
      M0 = nM;
    }
    lse[r] = M0 + logf(S0);
  }
}

// ---------------- target logit: dot(x[n], W[y[n]]) in f32 (exact) ----------------
__global__ __launch_bounds__(256) void tlogit_kernel(const float* __restrict__ x,
                                                     const int* __restrict__ y,
                                                     const float* __restrict__ W,
                                                     float* __restrict__ tl) {
  const int row = blockIdx.x * 4 + (threadIdx.x >> 6);
  const int l = threadIdx.x & 63;
  const int t = y[row];
  const float4* xr = reinterpret_cast<const float4*>(x + (size_t)row * HD);
  const float4* wr = reinterpret_cast<const float4*>(W + (size_t)t * HD);
  float s = 0.0f;
#pragma unroll
  for (int i = 0; i < HD / 4 / 64; ++i) {
    float4 a = xr[l + i * 64];
    float4 b = wr[l + i * 64];
    s += a.x * b.x + a.y * b.y + a.z * b.z + a.w * b.w;
  }
#pragma unroll
  for (int d = 1; d < 64; d <<= 1) s += __shfl_xor(s, d);
  if (l == 0) tl[row] = s;
}

// ---------------- mean(lse - tlogit) ----------------
__global__ __launch_bounds__(256) void finalize_kernel(const float* __restrict__ lse,
                                                       const float* __restrict__ tl,
                                                       float* __restrict__ out) {
  __shared__ float red[256];
  float s = 0.0f;
  for (int i = threadIdx.x; i < NR; i += 256) s += lse[i] - tl[i];
  red[threadIdx.x] = s;
  __syncthreads();
  for (int d = 128; d > 0; d >>= 1) {
    if ((int)threadIdx.x < d) red[threadIdx.x] += red[threadIdx.x + d];
    __syncthreads();
  }
  if (threadIdx.x == 0) out[0] = red[0] * (1.0f / NR);
}

extern "C" void kernel_launch(void* const* d_in, const int* in_sizes, int n_in,
                              void* d_out, int out_size, void* d_ws, size_t ws_size,
                              hipStream_t stream) {
  const float* x = (const float*)d_in[0];
  const int* y = (const int*)d_in[1];
  const float* W = (const float*)d_in[2];
  float* out = (float*)d_out;
  char* ws = (char*)d_ws;

  if (ws_size >= NEED_NEW) {
    u8* x8      = (u8*)(ws + OFF_X8);
    u8* w8      = (u8*)(ws + OFF_W8);
    float* pmax = (float*)(ws + OFF_PMX);
    float* psum = (float*)(ws + OFF_PSM);
    float* lse  = (float*)(ws + OFF_LSE);
    float* tl   = (float*)(ws + OFF_TL);
    cvt_x8_kernel<<<NR * HD / 16 / 256, 256, 0, stream>>>(x, x8);
    cvt_w8_kernel<<<4096, 256, 0, stream>>>(W, w8);
    gemm8<<<NMB8 * NVB8, 512, 0, stream>>>(x8, w8, pmax, psum);
    row_lse_kernel<<<NR / 64, 256, 0, stream>>>(pmax, psum, lse, NVB8);
    tlogit_kernel<<<NR / 4, 256, 0, stream>>>(x, y, W, tl);
    finalize_kernel<<<1, 256, 0, stream>>>(lse, tl, out);
  } else {
    u16* xb     = (u16*)(ws + FB_XB);
    float* pmax = (float*)(ws + FB_PMAX);
    float* psum = (float*)(ws + FB_PSUM);
    float* lse  = (float*)(ws + FB_LSE);
    float* tl   = (float*)(ws + FB_TL);
    cvt_x_kernel<<<NR * HD / 4 / 256, 256, 0, stream>>>(x, xb);
    gemm_partials_fb<<<NMBF * NVBF, 256, 0, stream>>>(xb, W, pmax, psum);
    row_lse_kernel<<<NR / 64, 256, 0, stream>>>(pmax, psum, lse, NVBF);
    tlogit_kernel<<<NR / 4, 256, 0, stream>>>(x, y, W, tl);
    finalize_kernel<<<1, 256, 0, stream>>>(lse, tl, out);
  }
}

// Round 13
// 1919.233 us; speedup vs baseline: 9.2234x; 1.0429x over previous
//
#include <hip/hip_runtime.h>
#include <hip/hip_fp8.h>

typedef unsigned short u16;
typedef unsigned char u8;
typedef unsigned int u32;
typedef long long i64;
typedef __attribute__((ext_vector_type(2))) i64 i64x2;
typedef __attribute__((ext_vector_type(8))) short short8;
typedef __attribute__((ext_vector_type(4))) float f32x4;

constexpr int HD = 2048;     // hidden / K (bytes in fp8)
constexpr int NR = 4096;     // rows B*S
constexpr int VO = 128000;   // vocab

// ---------------- fp8 path geometry: 256^2 tile, K-tile = 64 B ----------------
constexpr int NMB8 = NR / 256;    // 16
constexpr int NVB8 = VO / 256;    // 500
constexpr int NT8  = HD / 64;     // 32 K-tiles
constexpr float XSCALE = 32.0f;
constexpr float WSCALE = 16384.0f;
constexpr float UNSCALE = 1.0f / (XSCALE * WSCALE);

// ws layout (fp8 path)
constexpr size_t OFF_X8  = 0;                          // 8,388,608
constexpr size_t OFF_W8  = 8388608;                    // 262,144,000
constexpr size_t OFF_PMX = OFF_W8 + 262144000;         // 8,192,000
constexpr size_t OFF_PSM = OFF_PMX + 8192000;
constexpr size_t OFF_LSE = OFF_PSM + 8192000;
constexpr size_t OFF_TL  = OFF_LSE + 16384;
constexpr size_t NEED_NEW = OFF_TL + 16384;            // ~287 MB

// ws layout, fallback (round-1 bf16 128^2, proven)
constexpr int NVBF = VO / 128;
constexpr int NMBF = NR / 128;
constexpr size_t FB_XB   = 0;
constexpr size_t FB_PMAX = 16777216;
constexpr size_t FB_PSUM = FB_PMAX + 16384000;
constexpr size_t FB_LSE  = FB_PSUM + 16384000;
constexpr size_t FB_TL   = FB_LSE + (size_t)NR * 4;

// fallback swizzle
__device__ __forceinline__ u32 swz16(u32 a) { return a ^ (((a >> 7) & 3u) << 4); }

__device__ __forceinline__ u8 f2e4m3(float f) {
  return (u8)__hip_cvt_float_to_fp8(f, __HIP_SATFINITE, __HIP_E4M3);
}

// ---------------- x f32 -> fp8, kk-interleaved layout ----------------
// Per row, per 64B K-block: cell q (16B) holds elements k = kk*32 + q*8 + b
// at byte kk*8+b. One 16B LDS cell = a lane's full K=64 operand (both kk
// halves) -> single ds_read_b128 per fragment.
__global__ __launch_bounds__(256) void cvt_x8_kernel(const float* __restrict__ x,
                                                     u8* __restrict__ x8) {
  const long c = (long)blockIdx.x * 256 + threadIdx.x;   // 16B cell index
  const long row = c >> 7;                                // 128 cells/row
  const int ci = (int)(c & 127);
  const int tb = ci >> 2, q = ci & 3;
  const float* base = x + row * HD + tb * 64 + q * 8;
  float4 a0 = *reinterpret_cast<const float4*>(base);
  float4 a1 = *reinterpret_cast<const float4*>(base + 4);
  float4 a2 = *reinterpret_cast<const float4*>(base + 32);
  float4 a3 = *reinterpret_cast<const float4*>(base + 36);
  union { u8 b[16]; uint4 v; } p;
  p.b[0] = f2e4m3(a0.x * XSCALE); p.b[1] = f2e4m3(a0.y * XSCALE);
  p.b[2] = f2e4m3(a0.z * XSCALE); p.b[3] = f2e4m3(a0.w * XSCALE);
  p.b[4] = f2e4m3(a1.x * XSCALE); p.b[5] = f2e4m3(a1.y * XSCALE);
  p.b[6] = f2e4m3(a1.z * XSCALE); p.b[7] = f2e4m3(a1.w * XSCALE);
  p.b[8]  = f2e4m3(a2.x * XSCALE); p.b[9]  = f2e4m3(a2.y * XSCALE);
  p.b[10] = f2e4m3(a2.z * XSCALE); p.b[11] = f2e4m3(a2.w * XSCALE);
  p.b[12] = f2e4m3(a3.x * XSCALE); p.b[13] = f2e4m3(a3.y * XSCALE);
  p.b[14] = f2e4m3(a3.z * XSCALE); p.b[15] = f2e4m3(a3.w * XSCALE);
  reinterpret_cast<uint4*>(x8)[c] = p.v;
}

// ---------------- W f32 -> fp8, same kk-interleaved layout ----------------
__global__ __launch_bounds__(256) void cvt_w8_kernel(const float* __restrict__ W,
                                                     u8* __restrict__ w8) {
  const long total = (long)VO * HD / 16;                 // cells
  long c = (long)blockIdx.x * 256 + threadIdx.x;
  const long stride = (long)gridDim.x * 256;
  for (; c < total; c += stride) {
    const long row = c >> 7;
    const int ci = (int)(c & 127);
    const int tb = ci >> 2, q = ci & 3;
    const float* base = W + row * HD + tb * 64 + q * 8;
    float4 a0 = *reinterpret_cast<const float4*>(base);
    float4 a1 = *reinterpret_cast<const float4*>(base + 4);
    float4 a2 = *reinterpret_cast<const float4*>(base + 32);
    float4 a3 = *reinterpret_cast<const float4*>(base + 36);
    union { u8 b[16]; uint4 v; } p;
    p.b[0] = f2e4m3(a0.x * WSCALE); p.b[1] = f2e4m3(a0.y * WSCALE);
    p.b[2] = f2e4m3(a0.z * WSCALE); p.b[3] = f2e4m3(a0.w * WSCALE);
    p.b[4] = f2e4m3(a1.x * WSCALE); p.b[5] = f2e4m3(a1.y * WSCALE);
    p.b[6] = f2e4m3(a1.z * WSCALE); p.b[7] = f2e4m3(a1.w * WSCALE);
    p.b[8]  = f2e4m3(a2.x * WSCALE); p.b[9]  = f2e4m3(a2.y * WSCALE);
    p.b[10] = f2e4m3(a2.z * WSCALE); p.b[11] = f2e4m3(a2.w * WSCALE);
    p.b[12] = f2e4m3(a3.x * WSCALE); p.b[13] = f2e4m3(a3.y * WSCALE);
    p.b[14] = f2e4m3(a3.z * WSCALE); p.b[15] = f2e4m3(a3.w * WSCALE);
    reinterpret_cast<uint4*>(w8)[c] = p.v;
  }
}

// ============ 8-wave 256^2 fp8 fused GEMM + softmax partials ============
// Round-12 schedule (3-buffer LDS, counted vmcnt(4), reg-dbuf frags in the
// (512,2) 256-reg class) with ONE change: the 12 ds_read_b128 of tile T+1
// are INTERLEAVED into the 64 MFMAs of tile T (read-pair -> 8 MFMAs -> ...),
// pinned with sched_barrier(0). Round-12 PMC fit: period 4440 cyc = MFMA
// 2483 + LDS-pipe 1950 SERIAL — bunched read issue stalls each wave's
// in-order issue before its MFMAs while all 8 waves saturate the LDS pipe.
// Interleaving keeps both pipes fed (m196/T3: the fine interleave is the
// lever). Correctness unchanged: reads complete before body-end lgkm0;
// read buf((T+1)%3) disjoint from stage buf((T+2)%3).
__global__ __launch_bounds__(512, 2) void gemm8(
    const u8* __restrict__ x8, const u8* __restrict__ w8,
    float* __restrict__ pmax, float* __restrict__ psum) {
  __shared__ uint4 smem4[6144];                 // 96 KB: 3 bufs x {A 16K, B 16K}
  __shared__ float smax[256][4];
  __shared__ float ssum[256][4];
  char* Sm = reinterpret_cast<char*>(smem4);

  const int tid = threadIdx.x;
  const int w = tid >> 6, l = tid & 63;
  const int wr = w >> 2, wc = w & 3;            // 2M x 4N waves, 128x64 each
  const int q = l >> 4, r15 = l & 15;

  // XCD-bijective swizzle: 8000 = 8 * 1000; mb fast (W panel L2-reuse)
  const int bid = blockIdx.x;
  const int s = (bid & 7) * 1000 + (bid >> 3);
  const int mb = s & (NMB8 - 1);
  const int vb = s >> 4;
  const int rowbase = mb * 256, vbase = vb * 256;

  // -------- staging: 4 calls/tile (A rows 0-127, 128-255; B same) --------
  const u8* aS0; const u8* aS1; const u8* bS0; const u8* bS1;
  {
    u32 lin0 = (u32)tid * 16u;
    u32 r0 = lin0 >> 6, q0 = ((lin0 >> 4) & 3u) ^ (r0 & 3u);
    u32 lin1 = 8192u + (u32)tid * 16u;
    u32 r1 = lin1 >> 6, q1 = ((lin1 >> 4) & 3u) ^ (r1 & 3u);
    aS0 = x8 + (size_t)(rowbase + (int)r0) * HD + q0 * 16u;
    aS1 = x8 + (size_t)(rowbase + (int)r1) * HD + q1 * 16u;
    bS0 = w8 + (size_t)(vbase + (int)r0) * HD + q0 * 16u;
    bS1 = w8 + (size_t)(vbase + (int)r1) * HD + q1 * 16u;
  }
  const u32 dA0 = (u32)(w * 1024);
  const u32 dA1 = 8192u + (u32)(w * 1024);
  const u32 dB0 = 16384u + (u32)(w * 1024);
  const u32 dB1 = 24576u + (u32)(w * 1024);

  auto stg = [&](const u8* src, u32 dstOff) {
    __builtin_amdgcn_global_load_lds(
        (const __attribute__((address_space(1))) u32*)src,
        (__attribute__((address_space(3))) u32*)(Sm + dstOff), 16, 0, 0);
  };
#define STAGE(T, OFF) do {                      \
    stg(aS0 + (size_t)(T) * 64, (OFF) + dA0);   \
    stg(aS1 + (size_t)(T) * 64, (OFF) + dA1);   \
    stg(bS0 + (size_t)(T) * 64, (OFF) + dB0);   \
    stg(bS1 + (size_t)(T) * 64, (OFF) + dB1);   \
  } while (0)

  // -------- fragment read bases: one b128 per frag, slot = q^(r15&3) --------
  const u32 slot = ((u32)q ^ ((u32)r15 & 3u)) << 4;
  const u32 aBase = ((u32)(wr * 128 + r15) << 6) + slot;            // + jj*1024
  const u32 bBase = 16384u + ((u32)(wc * 64 + r15) << 6) + slot;    // + nn*1024

  i64x2 s0a[8], s0b[4], s1a[8], s1b[4];
  f32x4 acc[8][4];
#pragma unroll
  for (int m = 0; m < 8; ++m)
#pragma unroll
    for (int n = 0; n < 4; ++n) acc[m][n] = (f32x4)(0.0f);

#define SCH() __builtin_amdgcn_sched_barrier(0)
#define RDA(NA, JJ) NA[JJ] = *reinterpret_cast<const i64x2*>(Sm + rdOff + aBase + (JJ) * 1024)
#define RDB(NB, NN) NB[NN] = *reinterpret_cast<const i64x2*>(Sm + rdOff + bBase + (NN) * 1024)

#define MMG(CA, CB, JJ) do {                                                   \
    __builtin_amdgcn_s_setprio(1);                                             \
    _Pragma("unroll") for (int nn = 0; nn < 4; ++nn) {                         \
      acc[JJ][nn] = __builtin_amdgcn_mfma_f32_16x16x32_fp8_fp8(                \
          CA[JJ][0], CB[nn][0], acc[JJ][nn], 0, 0, 0);                         \
      acc[JJ][nn] = __builtin_amdgcn_mfma_f32_16x16x32_fp8_fp8(                \
          CA[JJ][1], CB[nn][1], acc[JJ][nn], 0, 0, 0);                         \
    }                                                                          \
    __builtin_amdgcn_s_setprio(0);                                             \
  } while (0)

#define RD_NEXT(NA, NB) do {                                                   \
    _Pragma("unroll") for (int jj = 0; jj < 8; ++jj) RDA(NA, jj);              \
    _Pragma("unroll") for (int nn = 0; nn < 4; ++nn) RDB(NB, nn);              \
  } while (0)

#define MM(CA, CB) do {                                                        \
    MMG(CA, CB, 0); MMG(CA, CB, 1); MMG(CA, CB, 2); MMG(CA, CB, 3);            \
    MMG(CA, CB, 4); MMG(CA, CB, 5); MMG(CA, CB, 6); MMG(CA, CB, 7);            \
  } while (0)

// Steady body (T+2 < NT8): STAGE(T+2) first, counted vmcnt(4) = "T+1 landed"
// (outstanding T+1:4 + T+2:4 = 8), BAR, then the interleave: {2 reads ->
// 8 MFMAs} x4, {1 read -> 8 MFMAs} x4, pinned by sched_barrier(0).
#define BODY_MAIN(T, CA, CB, NA, NB) do {                                      \
    STAGE((T) + 2, stOff);                                                     \
    asm volatile("s_waitcnt vmcnt(4)" ::: "memory");                           \
    __builtin_amdgcn_s_barrier();                                              \
    SCH();                                                                     \
    RDB(NB, 0); RDA(NA, 0); SCH(); MMG(CA, CB, 0); SCH();                      \
    RDB(NB, 1); RDA(NA, 1); SCH(); MMG(CA, CB, 1); SCH();                      \
    RDB(NB, 2); RDA(NA, 2); SCH(); MMG(CA, CB, 2); SCH();                      \
    RDB(NB, 3); RDA(NA, 3); SCH(); MMG(CA, CB, 3); SCH();                      \
    RDA(NA, 4); SCH(); MMG(CA, CB, 4); SCH();                                  \
    RDA(NA, 5); SCH(); MMG(CA, CB, 5); SCH();                                  \
    RDA(NA, 6); SCH(); MMG(CA, CB, 6); SCH();                                  \
    RDA(NA, 7); SCH(); MMG(CA, CB, 7);                                         \
    asm volatile("s_waitcnt lgkmcnt(0)" ::: "memory");                         \
    SCH();                                                                     \
    rdOff = (rdOff == 65536u) ? 0u : rdOff + 32768u;                           \
    stOff = (stOff == 65536u) ? 0u : stOff + 32768u;                           \
  } while (0)

  // -------- prologue: stage T0 -> buf0, T1 -> buf1; preload frags(T0) --------
  STAGE(0, 0u);
  STAGE(1, 32768u);
  asm volatile("s_waitcnt vmcnt(4)" ::: "memory");
  __builtin_amdgcn_s_barrier();
  SCH();
  {
    u32 rdOff = 0u;   // shadow for RDA/RDB macros in prologue
#pragma unroll
    for (int jj = 0; jj < 8; ++jj) RDA(s0a, jj);
#pragma unroll
    for (int nn = 0; nn < 4; ++nn) RDB(s0b, nn);
  }
  // retire preload reads of buf0 before body(1) can stage into it
  asm volatile("s_waitcnt lgkmcnt(0)" ::: "memory");
  SCH();

  u32 rdOff = 32768u;                           // body(0) reads T1 from buf1
  u32 stOff = 65536u;                           // body(0) stages T2 -> buf2

  // -------- K-loop: bodies 0..29 steady (interleaved), 30/31 tail ----------
  for (int t = 0; t < NT8 - 2; t += 2) {
    BODY_MAIN(t,     s0a, s0b, s1a, s1b);
    BODY_MAIN(t + 1, s1a, s1b, s0a, s0b);
  }
  // body 30 (even -> current s0): no stage; only T31's 4 loads outstanding
  asm volatile("s_waitcnt vmcnt(0)" ::: "memory");
  __builtin_amdgcn_s_barrier();
  SCH();
  RD_NEXT(s1a, s1b);
  MM(s0a, s0b);
  asm volatile("s_waitcnt lgkmcnt(0)" ::: "memory");
  SCH();
  // body 31: current s1
  MM(s1a, s1b);
#undef BODY_MAIN
#undef MM
#undef RD_NEXT
#undef MMG
#undef RDA
#undef RDB
#undef SCH
#undef STAGE

  // -------- epilogue: unscale, per-row max + sum(exp) over 256 vocab cols ----
  // C/D: col = lane&15, row = (lane>>4)*4 + reg. Wave rows: wr*128+jj*16+q*4+j;
  // wave cols: wc*64 + nn*16 + (lane&15).
#pragma unroll
  for (int jj = 0; jj < 8; ++jj) {
#pragma unroll
    for (int j = 0; j < 4; ++j) {
      float v0 = acc[jj][0][j] * UNSCALE, v1 = acc[jj][1][j] * UNSCALE;
      float v2 = acc[jj][2][j] * UNSCALE, v3 = acc[jj][3][j] * UNSCALE;
      float mx = fmaxf(fmaxf(v0, v1), fmaxf(v2, v3));
#pragma unroll
      for (int d = 1; d < 16; d <<= 1) mx = fmaxf(mx, __shfl_xor(mx, d));
      float se = __expf(v0 - mx) + __expf(v1 - mx) + __expf(v2 - mx) + __expf(v3 - mx);
#pragma unroll
      for (int d = 1; d < 16; d <<= 1) se += __shfl_xor(se, d);
      if (r15 == 0) {
        int r = wr * 128 + jj * 16 + q * 4 + j;
        smax[r][wc] = mx;
        ssum[r][wc] = se;
      }
    }
  }
  __syncthreads();
  if (tid < 256) {
    float m0 = smax[tid][0], m1 = smax[tid][1], m2 = smax[tid][2], m3 = smax[tid][3];
    float M = fmaxf(fmaxf(m0, m1), fmaxf(m2, m3));
    float S = ssum[tid][0] * __expf(m0 - M) + ssum[tid][1] * __expf(m1 - M) +
              ssum[tid][2] * __expf(m2 - M) + ssum[tid][3] * __expf(m3 - M);
    size_t o = (size_t)vb * NR + (size_t)(rowbase + tid);
    pmax[o] = M;
    psum[o] = S;
  }
}

// ================= fallback path (round-1 bf16, proven) =================
__global__ __launch_bounds__(256) void cvt_x_kernel(const float* __restrict__ x,
                                                    u16* __restrict__ xb) {
  int i = blockIdx.x * 256 + threadIdx.x;
  float4 v = reinterpret_cast<const float4*>(x)[i];
  union { __bf16 b[4]; unsigned long long ll; } p;
  p.b[0] = (__bf16)v.x; p.b[1] = (__bf16)v.y;
  p.b[2] = (__bf16)v.z; p.b[3] = (__bf16)v.w;
  reinterpret_cast<unsigned long long*>(xb)[i] = p.ll;
}

__global__ __launch_bounds__(256) void gemm_partials_fb(
    const u16* __restrict__ xb, const float* __restrict__ W,
    float* __restrict__ pmax, float* __restrict__ psum) {
  __shared__ uint4 smem[1024];
  __shared__ float smax[128][2];
  __shared__ float ssum[128][2];
  char* Ab = reinterpret_cast<char*>(smem);
  char* Bb = Ab + 8192;

  const int tid = threadIdx.x;
  const int w = tid >> 6;
  const int l = tid & 63;
  const int wr = w >> 1, wc = w & 1;

  const int bid = blockIdx.x;
  const int s = (bid & 7) * (NMBF * NVBF / 8) + (bid >> 3);
  const int mb = s & (NMBF - 1);
  const int vb = s >> 5;
  const int rowbase = mb * 128;
  const int vbase = vb * 128;

  const u16* aSrc[2];
  unsigned aBase[2];
#pragma unroll
  for (int i = 0; i < 2; ++i) {
    unsigned lin = (unsigned)w * 2048u + (unsigned)i * 1024u + (unsigned)l * 16u;
    unsigned sb = swz16(lin);
    unsigned r = sb >> 6;
    unsigned c = (sb >> 1) & 31u;
    aSrc[i] = xb + (size_t)(rowbase + (int)r) * HD + c;
    aBase[i] = (unsigned)w * 2048u + (unsigned)i * 1024u;
  }
  const float* bSrc[2];
  unsigned bLin[2];
#pragma unroll
  for (int i = 0; i < 2; ++i) {
    unsigned lin = (unsigned)i * 4096u + (unsigned)tid * 16u;
    unsigned sb = swz16(lin);
    unsigned n = sb >> 6;
    unsigned k = (sb >> 1) & 31u;
    bSrc[i] = W + (size_t)(vbase + (int)n) * HD + k;
    bLin[i] = lin;
  }
  const unsigned q = (unsigned)(l >> 4);
  unsigned aOff[4], bOff[4];
#pragma unroll
  for (int m = 0; m < 4; ++m) {
    unsigned R = (unsigned)(wr * 64 + m * 16 + (l & 15));
    aOff[m] = swz16(R * 64u + q * 16u);
    R = (unsigned)(wc * 64 + m * 16 + (l & 15));
    bOff[m] = swz16(R * 64u + q * 16u);
  }
  f32x4 acc[4][4];
#pragma unroll
  for (int m = 0; m < 4; ++m)
#pragma unroll
    for (int n = 0; n < 4; ++n) acc[m][n] = (f32x4)(0.0f);

  for (int kt = 0; kt < HD; kt += 32) {
    float4 g0 = *reinterpret_cast<const float4*>(bSrc[0]);
    float4 g1 = *reinterpret_cast<const float4*>(bSrc[0] + 4);
    float4 g2 = *reinterpret_cast<const float4*>(bSrc[1]);
    float4 g3 = *reinterpret_cast<const float4*>(bSrc[1] + 4);
#pragma unroll
    for (int i = 0; i < 2; ++i) {
      __builtin_amdgcn_global_load_lds(
          (const __attribute__((address_space(1))) u32*)aSrc[i],
          (__attribute__((address_space(3))) u32*)(Ab + aBase[i]), 16, 0, 0);
    }
    union { __bf16 b[8]; uint4 v; } p0, p1;
    p0.b[0] = (__bf16)g0.x; p0.b[1] = (__bf16)g0.y; p0.b[2] = (__bf16)g0.z; p0.b[3] = (__bf16)g0.w;
    p0.b[4] = (__bf16)g1.x; p0.b[5] = (__bf16)g1.y; p0.b[6] = (__bf16)g1.z; p0.b[7] = (__bf16)g1.w;
    p1.b[0] = (__bf16)g2.x; p1.b[1] = (__bf16)g2.y; p1.b[2] = (__bf16)g2.z; p1.b[3] = (__bf16)g2.w;
    p1.b[4] = (__bf16)g3.x; p1.b[5] = (__bf16)g3.y; p1.b[6] = (__bf16)g3.z; p1.b[7] = (__bf16)g3.w;
    *reinterpret_cast<uint4*>(Bb + bLin[0]) = p0.v;
    *reinterpret_cast<uint4*>(Bb + bLin[1]) = p1.v;
    __syncthreads();

    short8 af[4], bfr[4];
#pragma unroll
    for (int m = 0; m < 4; ++m) af[m] = *reinterpret_cast<const short8*>(Ab + aOff[m]);
#pragma unroll
    for (int n = 0; n < 4; ++n) bfr[n] = *reinterpret_cast<const short8*>(Bb + bOff[n]);
#pragma unroll
    for (int m = 0; m < 4; ++m)
#pragma unroll
      for (int n = 0; n < 4; ++n)
        acc[m][n] = __builtin_amdgcn_mfma_f32_16x16x32_bf16(af[m], bfr[n], acc[m][n], 0, 0, 0);
    __syncthreads();

    aSrc[0] += 32; aSrc[1] += 32;
    bSrc[0] += 32; bSrc[1] += 32;
  }
#pragma unroll
  for (int m = 0; m < 4; ++m) {
#pragma unroll
    for (int j = 0; j < 4; ++j) {
      float v0 = acc[m][0][j], v1 = acc[m][1][j], v2 = acc[m][2][j], v3 = acc[m][3][j];
      float mx = fmaxf(fmaxf(v0, v1), fmaxf(v2, v3));
#pragma unroll
      for (int d = 1; d < 16; d <<= 1) mx = fmaxf(mx, __shfl_xor(mx, d));
      float se = __expf(v0 - mx) + __expf(v1 - mx) + __expf(v2 - mx) + __expf(v3 - mx);
#pragma unroll
      for (int d = 1; d < 16; d <<= 1) se += __shfl_xor(se, d);
      if ((l & 15) == 0) {
        int rloc = wr * 64 + m * 16 + (int)q * 4 + j;
        smax[rloc][wc] = mx;
        ssum[rloc][wc] = se;
      }
    }
  }
  __syncthreads();
  if (tid < 128) {
    float m0 = smax[tid][0], m1 = smax[tid][1];
    float M = fmaxf(m0, m1);
    float S = ssum[tid][0] * __expf(m0 - M) + ssum[tid][1] * __expf(m1 - M);
    size_t o = (size_t)vb * NR + (size_t)(rowbase + tid);
    pmax[o] = M;
    psum[o] = S;
  }
}

// ---------------- merge partials -> LSE per row ----------------
__global__ __launch_bounds__(256) void row_lse_kernel(const float* __restrict__ pmax,
                                                      const float* __restrict__ psum,
                                                      float* __restrict__ lse, int nvb) {
  __shared__ float lm[4][64];
  __shared__ float ls[4][64];
  const int rb = blockIdx.x * 64;
  const int rl = threadIdx.x & 63;
  const int g = threadIdx.x >> 6;
  const int r = rb + rl;
  float M = -3.0e38f, S = 0.0f;
  for (int v = g; v < nvb; v += 4) {
    float m = pmax[(size_t)v * NR + r];
    float s = psum[(size_t)v * NR + r];
    float nM = fmaxf(M, m);
    S = S * __expf(M - nM) + s * __expf(m - nM);
    M = nM;
  }
  lm[g][rl] = M; ls[g][rl] = S;
  __syncthreads();
  if (threadIdx.x < 64) {
    float M0 = lm[0][rl], S0 = ls[0][rl];
#pragma unroll
    for (int g2 = 1; g2 < 4; ++g2) {
      float m = lm[g2][rl], s2 = ls[g2][rl];
      float nM = fmaxf(M0, m);
      S0 = S0 * __expf(M0 - nM) + s2 * __expf(m - nM);
      M0 = nM;
    }
    lse[r] = M0 + logf(S0);
  }
}

// ---------------- target logit: dot(x[n], W[y[n]]) in f32 (exact) ----------------
__global__ __launch_bounds__(256) void tlogit_kernel(const float* __restrict__ x,
                                                     const int* __restrict__ y,
                                                     const float* __restrict__ W,
                                                     float* __restrict__ tl) {
  const int row = blockIdx.x * 4 + (threadIdx.x >> 6);
  const int l = threadIdx.x & 63;
  const int t = y[row];
  const float4* xr = reinterpret_cast<const float4*>(x + (size_t)row * HD);
  const float4* wr = reinterpret_cast<const float4*>(W + (size_t)t * HD);
  float s = 0.0f;
#pragma unroll
  for (int i = 0; i < HD / 4 / 64; ++i) {
    float4 a = xr[l + i * 64];
    float4 b = wr[l + i * 64];
    s += a.x * b.x + a.y * b.y + a.z * b.z + a.w * b.w;
  }
#pragma unroll
  for (int d = 1; d < 64; d <<= 1) s += __shfl_xor(s, d);
  if (l == 0) tl[row] = s;
}

// ---------------- mean(lse - tlogit) ----------------
__global__ __launch_bounds__(256) void finalize_kernel(const float* __restrict__ lse,
                                                       const float* __restrict__ tl,
                                                       float* __restrict__ out) {
  __shared__ float red[256];
  float s = 0.0f;
  for (int i = threadIdx.x; i < NR; i += 256) s += lse[i] - tl[i];
  red[threadIdx.x] = s;
  __syncthreads();
  for (int d = 128; d > 0; d >>= 1) {
    if ((int)threadIdx.x < d) red[threadIdx.x] += red[threadIdx.x + d];
    __syncthreads();
  }
  if (threadIdx.x == 0) out[0] = red[0] * (1.0f / NR);
}

extern "C" void kernel_launch(void* const* d_in, const int* in_sizes, int n_in,
                              void* d_out, int out_size, void* d_ws, size_t ws_size,
                              hipStream_t stream) {
  const float* x = (const float*)d_in[0];
  const int* y = (const int*)d_in[1];
  const float* W = (const float*)d_in[2];
  float* out = (float*)d_out;
  char* ws = (char*)d_ws;

  if (ws_size >= NEED_NEW) {
    u8* x8      = (u8*)(ws + OFF_X8);
    u8* w8      = (u8*)(ws + OFF_W8);
    float* pmax = (float*)(ws + OFF_PMX);
    float* psum = (float*)(ws + OFF_PSM);
    float* lse  = (float*)(ws + OFF_LSE);
    float* tl   = (float*)(ws + OFF_TL);
    cvt_x8_kernel<<<NR * HD / 16 / 256, 256, 0, stream>>>(x, x8);
    cvt_w8_kernel<<<4096, 256, 0, stream>>>(W, w8);
    gemm8<<<NMB8 * NVB8, 512, 0, stream>>>(x8, w8, pmax, psum);
    row_lse_kernel<<<NR / 64, 256, 0, stream>>>(pmax, psum, lse, NVB8);
    tlogit_kernel<<<NR / 4, 256, 0, stream>>>(x, y, W, tl);
    finalize_kernel<<<1, 256, 0, stream>>>(lse, tl, out);
  } else {
    u16* xb     = (u16*)(ws + FB_XB);
    float* pmax = (float*)(ws + FB_PMAX);
    float* psum = (float*)(ws + FB_PSUM);
    float* lse  = (float*)(ws + FB_LSE);
    float* tl   = (float*)(ws + FB_TL);
    cvt_x_kernel<<<NR * HD / 4 / 256, 256, 0, stream>>>(x, xb);
    gemm_partials_fb<<<NMBF * NVBF, 256, 0, stream>>>(xb, W, pmax, psum);
    row_lse_kernel<<<NR / 64, 256, 0, stream>>>(pmax, psum, lse, NVBF);
    tlogit_kernel<<<NR / 4, 256, 0, stream>>>(x, y, W, tl);
    finalize_kernel<<<1, 256, 0, stream>>>(lse, tl, out);
  }
}